// Round 1
// baseline (137.477 us; speedup 1.0000x reference)
//
#include <hip/hip_runtime.h>
#include <hip/hip_bf16.h>
#include <cstdint>

#define N_DIM 4096
#define K_DIM 2048

typedef __bf16 bf16x8 __attribute__((ext_vector_type(8)));
typedef float floatx4 __attribute__((ext_vector_type(4)));
typedef unsigned short ushort8 __attribute__((ext_vector_type(8)));
typedef int intx4 __attribute__((ext_vector_type(4)));

__device__ __forceinline__ unsigned short f2bf(float f) {
    unsigned int u = __builtin_bit_cast(unsigned int, f);
    unsigned int r = (u + 0x7fffu + ((u >> 16) & 1u)) >> 16;  // RNE
    return (unsigned short)r;
}

__device__ __forceinline__ void gld_lds16(const void* g, void* l) {
    __builtin_amdgcn_global_load_lds(
        (const __attribute__((address_space(1))) unsigned int*)g,
        (__attribute__((address_space(3))) unsigned int*)l,
        16, 0, 0);
}

// ---------------- Kernel 0: cast fp32 -> bf16, compute row squared norms ----
__global__ __launch_bounds__(256)
void prep_kernel(const float* __restrict__ X, unsigned short* __restrict__ Abf,
                 float* __restrict__ sq) {
    const int row = blockIdx.x;
    const int tid = threadIdx.x;
    const float* xr = X + (size_t)row * K_DIM;
    floatx4 a = *(const floatx4*)(xr + tid * 8);
    floatx4 b = *(const floatx4*)(xr + tid * 8 + 4);
    float s = 0.f;
    ushort8 o;
#pragma unroll
    for (int e = 0; e < 4; ++e) {
        s += a[e] * a[e] + b[e] * b[e];
        o[e] = f2bf(a[e]);
        o[4 + e] = f2bf(b[e]);
    }
    *(ushort8*)(Abf + (size_t)row * K_DIM + tid * 8) = o;
    // block reduce s
#pragma unroll
    for (int off = 32; off; off >>= 1) s += __shfl_down(s, off);
    __shared__ float wsum[4];
    const int wave = tid >> 6, lane = tid & 63;
    if (lane == 0) wsum[wave] = s;
    __syncthreads();
    if (tid == 0) sq[row] = wsum[0] + wsum[1] + wsum[2] + wsum[3];
}

// ---------------- Kernel 1: bf16 MFMA GEMM (X @ X^T) + distance epilogue ----
__global__ __launch_bounds__(256)
void gemm_dist(const unsigned short* __restrict__ Abf, const float* __restrict__ sq,
               float* __restrict__ D) {
    __shared__ unsigned short sA[128 * 32];
    __shared__ unsigned short sB[128 * 32];
    const int tid = threadIdx.x;
    const int wave = tid >> 6, lane = tid & 63;
    const int wr = wave >> 1, wc = wave & 1;
    const int bi = blockIdx.x & 31, bj = blockIdx.x >> 5;
    const int rowBase = bi * 128, colBase = bj * 128;

    floatx4 acc[4][4];
#pragma unroll
    for (int m = 0; m < 4; ++m)
#pragma unroll
        for (int n = 0; n < 4; ++n) acc[m][n] = (floatx4){0.f, 0.f, 0.f, 0.f};

    // staging: tile is [128 rows][32 k] bf16, linear LDS; 2 issues of 256x16B
    const int r0 = tid >> 2;           // local row for issue 0
    const int c0 = (tid & 3) * 8;      // k-col
    const unsigned short* aP0 = Abf + (size_t)(rowBase + r0) * K_DIM + c0;
    const unsigned short* aP1 = aP0 + (size_t)64 * K_DIM;
    const unsigned short* bP0 = Abf + (size_t)(colBase + r0) * K_DIM + c0;
    const unsigned short* bP1 = bP0 + (size_t)64 * K_DIM;
    unsigned short* sA0 = sA + wave * 512;          // wave-uniform LDS bases
    unsigned short* sA1 = sA + 2048 + wave * 512;
    unsigned short* sB0 = sB + wave * 512;
    unsigned short* sB1 = sB + 2048 + wave * 512;

    const int fr = lane & 15;
    const int fk = (lane >> 4) * 8;

    for (int kt = 0; kt < K_DIM; kt += 32) {
        gld_lds16(aP0 + kt, sA0);
        gld_lds16(aP1 + kt, sA1);
        gld_lds16(bP0 + kt, sB0);
        gld_lds16(bP1 + kt, sB1);
        __syncthreads();
        bf16x8 af[4], bfv[4];
#pragma unroll
        for (int m = 0; m < 4; ++m)
            af[m] = *(const bf16x8*)(sA + (wr * 64 + m * 16 + fr) * 32 + fk);
#pragma unroll
        for (int n = 0; n < 4; ++n)
            bfv[n] = *(const bf16x8*)(sB + (wc * 64 + n * 16 + fr) * 32 + fk);
#pragma unroll
        for (int m = 0; m < 4; ++m)
#pragma unroll
            for (int n = 0; n < 4; ++n)
                acc[m][n] = __builtin_amdgcn_mfma_f32_16x16x32_bf16(
                    af[m], bfv[n], acc[m][n], 0, 0, 0);
        __syncthreads();
    }

    // epilogue: D[i][j] = sqrt(max(sq_i + sq_j - 2*dot, 1e-12))
    const int rBase = rowBase + wr * 64;
    const int cBase = colBase + wc * 64;
#pragma unroll
    for (int m = 0; m < 4; ++m) {
#pragma unroll
        for (int n = 0; n < 4; ++n) {
            const int col = cBase + n * 16 + (lane & 15);
            const int row0 = rBase + m * 16 + (lane >> 4) * 4;
            const float sqc = sq[col];
#pragma unroll
            for (int r = 0; r < 4; ++r) {
                float d2 = sq[row0 + r] + sqc - 2.0f * acc[m][n][r];
                D[(size_t)(row0 + r) * N_DIM + col] = sqrtf(fmaxf(d2, 1e-12f));
            }
        }
    }
}

// ---------------- Kernel 2: per-row hardest-pos / hardest-neg --------------
__global__ __launch_bounds__(256)
void rowstats(const float* __restrict__ D, const int* __restrict__ tgt,
              float* __restrict__ ap, float* __restrict__ an,
              int* __restrict__ pOut, int* __restrict__ qOut) {
    const int i = blockIdx.x, tid = threadIdx.x;
    const int ti = tgt[i];
    const float* row = D + (size_t)i * N_DIM;
    float bmax = -INFINITY; int bp = -1;
    float bmin = INFINITY;  int bq = -1;
#pragma unroll
    for (int it = 0; it < 4; ++it) {
        const int j0 = (it * 256 + tid) * 4;
        floatx4 d = *(const floatx4*)(row + j0);
        intx4 t4 = *(const intx4*)(tgt + j0);
#pragma unroll
        for (int e = 0; e < 4; ++e) {
            const int j = j0 + e; const float dv = d[e];
            if (t4[e] == ti) {
                if (dv > bmax || (dv == bmax && j > bp)) { bmax = dv; bp = j; }
            } else {
                if (dv < bmin || (dv == bmin && j > bq)) { bmin = dv; bq = j; }
            }
        }
    }
    __shared__ float smax[256]; __shared__ int sip[256];
    __shared__ float smin[256]; __shared__ int siq[256];
    smax[tid] = bmax; sip[tid] = bp; smin[tid] = bmin; siq[tid] = bq;
    __syncthreads();
    for (int off = 128; off; off >>= 1) {
        if (tid < off) {
            float v = smax[tid + off]; int ix = sip[tid + off];
            if (v > smax[tid] || (v == smax[tid] && ix > sip[tid])) { smax[tid] = v; sip[tid] = ix; }
            float w = smin[tid + off]; int iy = siq[tid + off];
            if (w < smin[tid] || (w == smin[tid] && iy > siq[tid])) { smin[tid] = w; siq[tid] = iy; }
        }
        __syncthreads();
    }
    if (tid == 0) { ap[i] = smax[0]; pOut[i] = sip[0]; an[i] = smin[0]; qOut[i] = siq[0]; }
}

// ---------------- Kernel 3: third-class scan on row q[i], per-row loss -----
__global__ __launch_bounds__(256)
void pass2(const float* __restrict__ D, const int* __restrict__ tgt,
           const float* __restrict__ ap, const float* __restrict__ an,
           const int* __restrict__ pArr, const int* __restrict__ qArr,
           float* __restrict__ lossArr) {
    const int i = blockIdx.x, tid = threadIdx.x;
    const int q = qArr[i];
    const int ti = tgt[i], lq = tgt[q];
    const float* rowq = D + (size_t)q * N_DIM;
    float bmin = INFINITY; int br = -1;
#pragma unroll
    for (int it = 0; it < 4; ++it) {
        const int j0 = (it * 256 + tid) * 4;
        floatx4 d = *(const floatx4*)(rowq + j0);
        intx4 t4 = *(const intx4*)(tgt + j0);
#pragma unroll
        for (int e = 0; e < 4; ++e) {
            const int j = j0 + e; const float dv = d[e];
            if (t4[e] != ti && t4[e] != lq) {
                if (dv < bmin || (dv == bmin && j > br)) { bmin = dv; br = j; }
            }
        }
    }
    __shared__ float sm[256]; __shared__ int si[256];
    sm[tid] = bmin; si[tid] = br;
    __syncthreads();
    for (int off = 128; off; off >>= 1) {
        if (tid < off) {
            float v = sm[tid + off]; int ix = si[tid + off];
            if (v < sm[tid] || (v == sm[tid] && ix > si[tid])) { sm[tid] = v; si[tid] = ix; }
        }
        __syncthreads();
    }
    if (tid == 0) {
        const int r = si[0]; const float okmin = sm[0];
        const float an2 = D[(size_t)pArr[i] * N_DIM + q];
        const float an3 = D[(size_t)i * N_DIM + r];
        lossArr[i] = fmaxf(ap[i] - an[i], 0.f) + fabsf(an[i] - an2) + fabsf(an3 - okmin);
    }
}

// ---------------- Kernel 4: final sum / n -----------------------------------
__global__ __launch_bounds__(256)
void finred(const float* __restrict__ lossArr, float* __restrict__ out) {
    const int tid = threadIdx.x;
    float s = 0.f;
    for (int j = tid; j < N_DIM; j += 256) s += lossArr[j];
#pragma unroll
    for (int off = 32; off; off >>= 1) s += __shfl_down(s, off);
    __shared__ float w[4];
    const int wave = tid >> 6, lane = tid & 63;
    if (lane == 0) w[wave] = s;
    __syncthreads();
    if (tid == 0) out[0] = (w[0] + w[1] + w[2] + w[3]) * (1.0f / (float)N_DIM);
}

extern "C" void kernel_launch(void* const* d_in, const int* in_sizes, int n_in,
                              void* d_out, int out_size, void* d_ws, size_t ws_size,
                              hipStream_t stream) {
    const float* X = (const float*)d_in[0];
    const int* tgt = (const int*)d_in[1];
    float* out = (float*)d_out;

    char* w = (char*)d_ws;
    unsigned short* Abf = (unsigned short*)w;                 // 16 MB
    float* D = (float*)(w + ((size_t)16 << 20));              // 64 MB
    float* sq = (float*)(w + ((size_t)80 << 20));             // 16 KB
    float* ap = sq + N_DIM;
    float* an = ap + N_DIM;
    float* lossArr = an + N_DIM;
    int* pA = (int*)(lossArr + N_DIM);
    int* qA = pA + N_DIM;

    prep_kernel<<<N_DIM, 256, 0, stream>>>(X, Abf, sq);
    gemm_dist<<<(N_DIM / 128) * (N_DIM / 128), 256, 0, stream>>>(Abf, sq, D);
    rowstats<<<N_DIM, 256, 0, stream>>>(D, tgt, ap, an, pA, qA);
    pass2<<<N_DIM, 256, 0, stream>>>(D, tgt, ap, an, pA, qA, lossArr);
    finred<<<1, 256, 0, stream>>>(lossArr, out);
}

// Round 2
// 116.110 us; speedup vs baseline: 1.1840x; 1.1840x over previous
//
#include <hip/hip_runtime.h>
#include <hip/hip_bf16.h>
#include <cstdint>

#define N_DIM 4096
#define K_DIM 2048
#define NBLK 32                      // 4096/128
#define NTRI (NBLK * (NBLK + 1) / 2) // 528 upper-triangle blocks

typedef __bf16 bf16x8 __attribute__((ext_vector_type(8)));
typedef float floatx4 __attribute__((ext_vector_type(4)));
typedef unsigned short ushort8 __attribute__((ext_vector_type(8)));
typedef int intx4 __attribute__((ext_vector_type(4)));

__device__ __forceinline__ unsigned short f2bf(float f) {
    unsigned int u = __builtin_bit_cast(unsigned int, f);
    unsigned int r = (u + 0x7fffu + ((u >> 16) & 1u)) >> 16;  // RNE
    return (unsigned short)r;
}

__device__ __forceinline__ void gld_lds16(const void* g, void* l) {
    __builtin_amdgcn_global_load_lds(
        (const __attribute__((address_space(1))) unsigned int*)g,
        (__attribute__((address_space(3))) unsigned int*)l,
        16, 0, 0);
}

// ---------------- Kernel 0: cast fp32 -> bf16, compute row squared norms ----
__global__ __launch_bounds__(256)
void prep_kernel(const float* __restrict__ X, unsigned short* __restrict__ Abf,
                 float* __restrict__ sq) {
    const int row = blockIdx.x;
    const int tid = threadIdx.x;
    const float* xr = X + (size_t)row * K_DIM;
    floatx4 a = *(const floatx4*)(xr + tid * 8);
    floatx4 b = *(const floatx4*)(xr + tid * 8 + 4);
    float s = 0.f;
    ushort8 o;
#pragma unroll
    for (int e = 0; e < 4; ++e) {
        s += a[e] * a[e] + b[e] * b[e];
        o[e] = f2bf(a[e]);
        o[4 + e] = f2bf(b[e]);
    }
    *(ushort8*)(Abf + (size_t)row * K_DIM + tid * 8) = o;
#pragma unroll
    for (int off = 32; off; off >>= 1) s += __shfl_down(s, off);
    __shared__ float wsum[4];
    const int wave = tid >> 6, lane = tid & 63;
    if (lane == 0) wsum[wave] = s;
    __syncthreads();
    if (tid == 0) sq[row] = wsum[0] + wsum[1] + wsum[2] + wsum[3];
}

// ---------------- Kernel 1: bf16 MFMA GEMM (upper-tri blocks) + mirror ------
__global__ __launch_bounds__(256)
void gemm_dist(const unsigned short* __restrict__ Abf, const float* __restrict__ sq,
               float* __restrict__ D) {
    __shared__ unsigned short sA[128 * 32];
    __shared__ unsigned short sB[128 * 32];
    const int tid = threadIdx.x;
    const int wave = tid >> 6, lane = tid & 63;
    const int wr = wave >> 1, wc = wave & 1;

    // XCD-chunked swizzle (528 % 8 == 0 -> bijective simple form)
    const int idx = (blockIdx.x % 8) * (NTRI / 8) + blockIdx.x / 8;
    // triangular decode: idx = bj*(bj+1)/2 + bi, 0 <= bi <= bj
    int bj = (int)((sqrtf(8.0f * (float)idx + 1.0f) - 1.0f) * 0.5f);
    while ((bj + 1) * (bj + 2) / 2 <= idx) ++bj;
    while (bj * (bj + 1) / 2 > idx) --bj;
    const int bi = idx - bj * (bj + 1) / 2;
    const int rowBase = bi * 128, colBase = bj * 128;

    floatx4 acc[4][4];
#pragma unroll
    for (int m = 0; m < 4; ++m)
#pragma unroll
        for (int n = 0; n < 4; ++n) acc[m][n] = (floatx4){0.f, 0.f, 0.f, 0.f};

    const int r0 = tid >> 2;
    const int c0 = (tid & 3) * 8;
    const unsigned short* aP0 = Abf + (size_t)(rowBase + r0) * K_DIM + c0;
    const unsigned short* aP1 = aP0 + (size_t)64 * K_DIM;
    const unsigned short* bP0 = Abf + (size_t)(colBase + r0) * K_DIM + c0;
    const unsigned short* bP1 = bP0 + (size_t)64 * K_DIM;
    unsigned short* sA0 = sA + wave * 512;
    unsigned short* sA1 = sA + 2048 + wave * 512;
    unsigned short* sB0 = sB + wave * 512;
    unsigned short* sB1 = sB + 2048 + wave * 512;

    const int fr = lane & 15;
    const int fk = (lane >> 4) * 8;

    for (int kt = 0; kt < K_DIM; kt += 32) {
        gld_lds16(aP0 + kt, sA0);
        gld_lds16(aP1 + kt, sA1);
        gld_lds16(bP0 + kt, sB0);
        gld_lds16(bP1 + kt, sB1);
        __syncthreads();
        bf16x8 af[4], bfv[4];
#pragma unroll
        for (int m = 0; m < 4; ++m)
            af[m] = *(const bf16x8*)(sA + (wr * 64 + m * 16 + fr) * 32 + fk);
#pragma unroll
        for (int n = 0; n < 4; ++n)
            bfv[n] = *(const bf16x8*)(sB + (wc * 64 + n * 16 + fr) * 32 + fk);
#pragma unroll
        for (int m = 0; m < 4; ++m)
#pragma unroll
            for (int n = 0; n < 4; ++n)
                acc[m][n] = __builtin_amdgcn_mfma_f32_16x16x32_bf16(
                    af[m], bfv[n], acc[m][n], 0, 0, 0);
        __syncthreads();
    }

    // epilogue: D[i][j] = sqrt(max(sq_i + sq_j - 2*dot, 1e-12)); mirror if bi<bj
    const int rBase = rowBase + wr * 64;
    const int cBase = colBase + wc * 64;
    const bool mirror = (bi < bj);
#pragma unroll
    for (int m = 0; m < 4; ++m) {
#pragma unroll
        for (int n = 0; n < 4; ++n) {
            const int col = cBase + n * 16 + (lane & 15);
            const int row0 = rBase + m * 16 + (lane >> 4) * 4;
            const float sqc = sq[col];
#pragma unroll
            for (int r = 0; r < 4; ++r) {
                float d2 = sq[row0 + r] + sqc - 2.0f * acc[m][n][r];
                float d = sqrtf(fmaxf(d2, 1e-12f));
                D[(size_t)(row0 + r) * N_DIM + col] = d;
                if (mirror) D[(size_t)col * N_DIM + (row0 + r)] = d;
            }
        }
    }
}

// ---------------- Kernel 2: per-row hardest-pos / hardest-neg --------------
__global__ __launch_bounds__(256)
void rowstats(const float* __restrict__ D, const int* __restrict__ tgt,
              float* __restrict__ ap, float* __restrict__ an,
              int* __restrict__ pOut, int* __restrict__ qOut) {
    const int i = blockIdx.x, tid = threadIdx.x;
    const int ti = tgt[i];
    const float* row = D + (size_t)i * N_DIM;
    float bmax = -INFINITY; int bp = -1;
    float bmin = INFINITY;  int bq = -1;
#pragma unroll
    for (int it = 0; it < 4; ++it) {
        const int j0 = (it * 256 + tid) * 4;
        floatx4 d = *(const floatx4*)(row + j0);
        intx4 t4 = *(const intx4*)(tgt + j0);
#pragma unroll
        for (int e = 0; e < 4; ++e) {
            const int j = j0 + e; const float dv = d[e];
            if (t4[e] == ti) {
                if (dv > bmax || (dv == bmax && j > bp)) { bmax = dv; bp = j; }
            } else {
                if (dv < bmin || (dv == bmin && j > bq)) { bmin = dv; bq = j; }
            }
        }
    }
    __shared__ float smax[256]; __shared__ int sip[256];
    __shared__ float smin[256]; __shared__ int siq[256];
    smax[tid] = bmax; sip[tid] = bp; smin[tid] = bmin; siq[tid] = bq;
    __syncthreads();
    for (int off = 128; off; off >>= 1) {
        if (tid < off) {
            float v = smax[tid + off]; int ix = sip[tid + off];
            if (v > smax[tid] || (v == smax[tid] && ix > sip[tid])) { smax[tid] = v; sip[tid] = ix; }
            float w = smin[tid + off]; int iy = siq[tid + off];
            if (w < smin[tid] || (w == smin[tid] && iy > siq[tid])) { smin[tid] = w; siq[tid] = iy; }
        }
        __syncthreads();
    }
    if (tid == 0) { ap[i] = smax[0]; pOut[i] = sip[0]; an[i] = smin[0]; qOut[i] = siq[0]; }
}

// ---------------- Kernel 3: third-class scan on row q[i], per-row loss -----
__global__ __launch_bounds__(256)
void pass2(const float* __restrict__ D, const int* __restrict__ tgt,
           const float* __restrict__ ap, const float* __restrict__ an,
           const int* __restrict__ pArr, const int* __restrict__ qArr,
           float* __restrict__ lossArr) {
    const int i = blockIdx.x, tid = threadIdx.x;
    const int q = qArr[i];
    const int ti = tgt[i], lq = tgt[q];
    const float* rowq = D + (size_t)q * N_DIM;
    float bmin = INFINITY; int br = -1;
#pragma unroll
    for (int it = 0; it < 4; ++it) {
        const int j0 = (it * 256 + tid) * 4;
        floatx4 d = *(const floatx4*)(rowq + j0);
        intx4 t4 = *(const intx4*)(tgt + j0);
#pragma unroll
        for (int e = 0; e < 4; ++e) {
            const int j = j0 + e; const float dv = d[e];
            if (t4[e] != ti && t4[e] != lq) {
                if (dv < bmin || (dv == bmin && j > br)) { bmin = dv; br = j; }
            }
        }
    }
    __shared__ float sm[256]; __shared__ int si[256];
    sm[tid] = bmin; si[tid] = br;
    __syncthreads();
    for (int off = 128; off; off >>= 1) {
        if (tid < off) {
            float v = sm[tid + off]; int ix = si[tid + off];
            if (v < sm[tid] || (v == sm[tid] && ix > si[tid])) { sm[tid] = v; si[tid] = ix; }
        }
        __syncthreads();
    }
    if (tid == 0) {
        const int r = si[0]; const float okmin = sm[0];
        const float an2 = D[(size_t)pArr[i] * N_DIM + q];
        const float an3 = D[(size_t)i * N_DIM + r];
        lossArr[i] = fmaxf(ap[i] - an[i], 0.f) + fabsf(an[i] - an2) + fabsf(an3 - okmin);
    }
}

// ---------------- Kernel 4: final sum / n -----------------------------------
__global__ __launch_bounds__(256)
void finred(const float* __restrict__ lossArr, float* __restrict__ out) {
    const int tid = threadIdx.x;
    float s = 0.f;
    for (int j = tid; j < N_DIM; j += 256) s += lossArr[j];
#pragma unroll
    for (int off = 32; off; off >>= 1) s += __shfl_down(s, off);
    __shared__ float w[4];
    const int wave = tid >> 6, lane = tid & 63;
    if (lane == 0) w[wave] = s;
    __syncthreads();
    if (tid == 0) out[0] = (w[0] + w[1] + w[2] + w[3]) * (1.0f / (float)N_DIM);
}

extern "C" void kernel_launch(void* const* d_in, const int* in_sizes, int n_in,
                              void* d_out, int out_size, void* d_ws, size_t ws_size,
                              hipStream_t stream) {
    const float* X = (const float*)d_in[0];
    const int* tgt = (const int*)d_in[1];
    float* out = (float*)d_out;

    char* w = (char*)d_ws;
    unsigned short* Abf = (unsigned short*)w;                 // 16 MB
    float* D = (float*)(w + ((size_t)16 << 20));              // 64 MB
    float* sq = (float*)(w + ((size_t)80 << 20));             // 16 KB
    float* ap = sq + N_DIM;
    float* an = ap + N_DIM;
    float* lossArr = an + N_DIM;
    int* pA = (int*)(lossArr + N_DIM);
    int* qA = pA + N_DIM;

    prep_kernel<<<N_DIM, 256, 0, stream>>>(X, Abf, sq);
    gemm_dist<<<NTRI, 256, 0, stream>>>(Abf, sq, D);
    rowstats<<<N_DIM, 256, 0, stream>>>(D, tgt, ap, an, pA, qA);
    pass2<<<N_DIM, 256, 0, stream>>>(D, tgt, ap, an, pA, qA, lossArr);
    finred<<<1, 256, 0, stream>>>(lossArr, out);
}

// Round 3
// 109.774 us; speedup vs baseline: 1.2524x; 1.0577x over previous
//
#include <hip/hip_runtime.h>
#include <hip/hip_bf16.h>
#include <cstdint>

#define N_DIM 4096
#define K_DIM 2048
#define NIT 16   // 32 K-tiles of 64, 2 per iteration

typedef __bf16 bf16x8 __attribute__((ext_vector_type(8)));
typedef float floatx4 __attribute__((ext_vector_type(4)));
typedef unsigned short ushort8 __attribute__((ext_vector_type(8)));
typedef int intx4 __attribute__((ext_vector_type(4)));

__device__ __forceinline__ unsigned short f2bf(float f) {
    unsigned int u = __builtin_bit_cast(unsigned int, f);
    unsigned int r = (u + 0x7fffu + ((u >> 16) & 1u)) >> 16;  // RNE
    return (unsigned short)r;
}

__device__ __forceinline__ void gld_lds16(const void* g, void* l) {
    __builtin_amdgcn_global_load_lds(
        (const __attribute__((address_space(1))) unsigned int*)g,
        (__attribute__((address_space(3))) unsigned int*)l,
        16, 0, 0);
}

__device__ __forceinline__ void stage_half(const unsigned short* src, unsigned short* ldsWave) {
    gld_lds16(src, ldsWave);                       // rows 0-63 of the half
    gld_lds16(src + 64 * K_DIM, ldsWave + 4096);   // rows 64-127 (+8192 B)
}

// ---------------- Kernel 0: cast fp32 -> bf16, compute row squared norms ----
__global__ __launch_bounds__(256)
void prep_kernel(const float* __restrict__ X, unsigned short* __restrict__ Abf,
                 float* __restrict__ sq) {
    const int row = blockIdx.x;
    const int tid = threadIdx.x;
    const float* xr = X + (size_t)row * K_DIM;
    floatx4 a = *(const floatx4*)(xr + tid * 8);
    floatx4 b = *(const floatx4*)(xr + tid * 8 + 4);
    float s = 0.f;
    ushort8 o;
#pragma unroll
    for (int e = 0; e < 4; ++e) {
        s += a[e] * a[e] + b[e] * b[e];
        o[e] = f2bf(a[e]);
        o[4 + e] = f2bf(b[e]);
    }
    *(ushort8*)(Abf + (size_t)row * K_DIM + tid * 8) = o;
#pragma unroll
    for (int off = 32; off; off >>= 1) s += __shfl_down(s, off);
    __shared__ float wsum[4];
    const int wave = tid >> 6, lane = tid & 63;
    if (lane == 0) wsum[wave] = s;
    __syncthreads();
    if (tid == 0) sq[row] = wsum[0] + wsum[1] + wsum[2] + wsum[3];
}

// ---------------- Kernel 1: 256x256 8-phase bf16 MFMA GEMM + dist epilogue --
// 512 thr = 8 waves (2Mx4N). BK=64, 2 K-tiles/iter. LDS 128KB: buf{0,1} x
// {Ah0,Ah1,Bh0,Bh1} 16KB regions. XOR-swizzle (row&7)<<4 via pre-swizzled
// global source (linear gld_lds dest) + swizzled ds_read.
#define READ_A(OFF) { _Pragma("unroll") for (int m_ = 0; m_ < 4; ++m_) { \
    _Pragma("unroll") for (int kk_ = 0; kk_ < 2; ++kk_) { \
        af[m_][kk_] = *(const bf16x8*)(ldsc + (OFF) + rA[m_] + kb[kk_]); } } }
#define READ_B(OFF) { _Pragma("unroll") for (int n_ = 0; n_ < 2; ++n_) { \
    _Pragma("unroll") for (int kk_ = 0; kk_ < 2; ++kk_) { \
        bfv[n_][kk_] = *(const bf16x8*)(ldsc + (OFF) + rB[n_] + kb[kk_]); } } }
#define MFMA_Q(MH, NH) { _Pragma("unroll") for (int m_ = 0; m_ < 4; ++m_) { \
    _Pragma("unroll") for (int n_ = 0; n_ < 2; ++n_) { \
    _Pragma("unroll") for (int kk_ = 0; kk_ < 2; ++kk_) { \
        acc[MH][NH][m_][n_] = __builtin_amdgcn_mfma_f32_16x16x32_bf16( \
            af[m_][kk_], bfv[n_][kk_], acc[MH][NH][m_][n_], 0, 0, 0); } } } }
#define BAR() __builtin_amdgcn_s_barrier()
#define PRIO1() __builtin_amdgcn_s_setprio(1)
#define PRIO0() __builtin_amdgcn_s_setprio(0)

__global__ __launch_bounds__(512, 2)
void gemm_dist(const unsigned short* __restrict__ Abf, const float* __restrict__ sq,
               float* __restrict__ D) {
    __shared__ unsigned short lds[65536];   // 128 KB
    const char* ldsc = (const char*)lds;
    const int tid = threadIdx.x;
    const int wid = tid >> 6, lane = tid & 63;
    const int wr = wid >> 2, wc = wid & 3;
    const int fr = lane & 15;
    const int key = (fr & 7) << 4;
    const int klin = (lane >> 4) << 4;     // byte offset of 16B k-slot
    int kb[2];
    kb[0] = klin ^ key;
    kb[1] = (64 | klin) ^ key;
    int rA[4], rB[2];
#pragma unroll
    for (int m = 0; m < 4; ++m) rA[m] = (wr * 64 + m * 16 + fr) * 128;
#pragma unroll
    for (int n = 0; n < 2; ++n) rB[n] = (wc * 32 + n * 16 + fr) * 128;

    const int swz = (blockIdx.x & 7) * 32 + (blockIdx.x >> 3);  // XCD-chunked
    const int bi = swz >> 4, bj = swz & 15;
    const int rowC0 = bi * 256, colC0 = bj * 256;

    // per-thread staging source (inverse-swizzled k so linear LDS + swz read = identity)
    const int srow = tid >> 3;
    const int ksrc = ((tid & 7) ^ (srow & 7)) << 3;
    const unsigned short* aSt = Abf + (size_t)(rowC0 + srow) * K_DIM + ksrc;
    const unsigned short* bSt = Abf + (size_t)(colC0 + srow) * K_DIM + ksrc;
    unsigned short* ldsW = lds + wid * 512;   // wave-uniform base (wid*1024 B)

    floatx4 acc[2][2][4][2];
#pragma unroll
    for (int a0 = 0; a0 < 2; ++a0)
#pragma unroll
    for (int a1 = 0; a1 < 2; ++a1)
#pragma unroll
    for (int a2 = 0; a2 < 4; ++a2)
#pragma unroll
    for (int a3 = 0; a3 < 2; ++a3) acc[a0][a1][a2][a3] = (floatx4){0.f, 0.f, 0.f, 0.f};
    bf16x8 af[4][2], bfv[2][2];

    // LDS regions (ushort offsets): buf0: Ah0=0 Ah1=8192 Bh0=16384 Bh1=24576
    //                               buf1: Ah0=32768 Ah1=40960 Bh0=49152 Bh1=57344
    // prologue: tile0 full + tile1 {Ah0,Bh0}
    stage_half(aSt,          ldsW + 0);       // (0).Ah0
    stage_half(bSt,          ldsW + 16384);   // (0).Bh0
    stage_half(bSt + 262144, ldsW + 24576);   // (0).Bh1
    stage_half(aSt + 262144, ldsW + 8192);    // (0).Ah1
    stage_half(aSt + 64,     ldsW + 32768);   // (1).Ah0
    stage_half(bSt + 64,     ldsW + 49152);   // (1).Bh0
    asm volatile("s_waitcnt vmcnt(4)" ::: "memory");
    BAR();

    for (int it = 0; it < NIT; ++it) {
        const int t64 = it * 128;           // = t*64, t = 2*it
        const bool pf = (it < NIT - 1);
        // ph1: tile t quadrant (0,0)  [buf0.Ah0 + buf0.Bh0]
        READ_A(0); READ_B(32768);
        stage_half(aSt + 262144 + t64 + 64, ldsW + 40960);   // (t+1).Ah1
        BAR(); PRIO1(); MFMA_Q(0, 0); PRIO0(); BAR();
        // ph2: (0,1)
        READ_B(49152);
        stage_half(bSt + 262144 + t64 + 64, ldsW + 57344);   // (t+1).Bh1
        BAR(); PRIO1(); MFMA_Q(0, 1); PRIO0(); BAR();
        // ph3: (1,0)
        READ_A(16384); READ_B(32768);
        if (pf) stage_half(aSt + t64 + 128, ldsW + 0);       // (t+2).Ah0
        BAR(); PRIO1(); MFMA_Q(1, 0); PRIO0(); BAR();
        // ph4: (1,1)
        READ_B(49152);
        if (pf) stage_half(bSt + t64 + 128, ldsW + 16384);   // (t+2).Bh0
        BAR(); PRIO1(); MFMA_Q(1, 1); PRIO0();
        if (pf) { asm volatile("s_waitcnt vmcnt(4)" ::: "memory"); }
        else    { asm volatile("s_waitcnt vmcnt(0)" ::: "memory"); }
        BAR();
        // ph5: tile t+1 quadrant (0,0)  [buf1]
        READ_A(65536); READ_B(98304);
        if (pf) stage_half(aSt + 262144 + t64 + 128, ldsW + 8192);   // (t+2).Ah1
        BAR(); PRIO1(); MFMA_Q(0, 0); PRIO0(); BAR();
        // ph6: (0,1)
        READ_B(114688);
        if (pf) stage_half(bSt + 262144 + t64 + 128, ldsW + 24576);  // (t+2).Bh1
        BAR(); PRIO1(); MFMA_Q(0, 1); PRIO0(); BAR();
        // ph7: (1,0)
        READ_A(81920); READ_B(98304);
        if (pf) stage_half(aSt + t64 + 192, ldsW + 32768);           // (t+3).Ah0
        BAR(); PRIO1(); MFMA_Q(1, 0); PRIO0(); BAR();
        // ph8: (1,1)
        READ_B(114688);
        if (pf) stage_half(bSt + t64 + 192, ldsW + 49152);           // (t+3).Bh0
        BAR(); PRIO1(); MFMA_Q(1, 1); PRIO0();
        asm volatile("s_waitcnt vmcnt(4)" ::: "memory");
        BAR();
    }

    // epilogue: D[i][j] = sqrt(max(sq_i + sq_j - 2*dot, 1e-12))
#pragma unroll
    for (int MH = 0; MH < 2; ++MH)
#pragma unroll
    for (int NH = 0; NH < 2; ++NH)
#pragma unroll
    for (int m = 0; m < 4; ++m)
#pragma unroll
    for (int n = 0; n < 2; ++n) {
        const int col = colC0 + NH * 128 + wc * 32 + n * 16 + fr;
        const int row0 = rowC0 + MH * 128 + wr * 64 + m * 16 + (lane >> 4) * 4;
        const float sqc = sq[col];
#pragma unroll
        for (int r = 0; r < 4; ++r) {
            float d2 = sq[row0 + r] + sqc - 2.0f * acc[MH][NH][m][n][r];
            D[(size_t)(row0 + r) * N_DIM + col] = sqrtf(fmaxf(d2, 1e-12f));
        }
    }
}

// ---------------- Kernel 2: per-row hardest-pos / hardest-neg --------------
__global__ __launch_bounds__(256)
void rowstats(const float* __restrict__ D, const int* __restrict__ tgt,
              float* __restrict__ ap, float* __restrict__ an,
              int* __restrict__ pOut, int* __restrict__ qOut) {
    const int i = blockIdx.x, tid = threadIdx.x;
    const int ti = tgt[i];
    const float* row = D + (size_t)i * N_DIM;
    float bmax = -INFINITY; int bp = -1;
    float bmin = INFINITY;  int bq = -1;
#pragma unroll
    for (int it = 0; it < 4; ++it) {
        const int j0 = (it * 256 + tid) * 4;
        floatx4 d = *(const floatx4*)(row + j0);
        intx4 t4 = *(const intx4*)(tgt + j0);
#pragma unroll
        for (int e = 0; e < 4; ++e) {
            const int j = j0 + e; const float dv = d[e];
            if (t4[e] == ti) {
                if (dv > bmax || (dv == bmax && j > bp)) { bmax = dv; bp = j; }
            } else {
                if (dv < bmin || (dv == bmin && j > bq)) { bmin = dv; bq = j; }
            }
        }
    }
    __shared__ float smax[256]; __shared__ int sip[256];
    __shared__ float smin[256]; __shared__ int siq[256];
    smax[tid] = bmax; sip[tid] = bp; smin[tid] = bmin; siq[tid] = bq;
    __syncthreads();
    for (int off = 128; off; off >>= 1) {
        if (tid < off) {
            float v = smax[tid + off]; int ix = sip[tid + off];
            if (v > smax[tid] || (v == smax[tid] && ix > sip[tid])) { smax[tid] = v; sip[tid] = ix; }
            float w = smin[tid + off]; int iy = siq[tid + off];
            if (w < smin[tid] || (w == smin[tid] && iy > siq[tid])) { smin[tid] = w; siq[tid] = iy; }
        }
        __syncthreads();
    }
    if (tid == 0) { ap[i] = smax[0]; pOut[i] = sip[0]; an[i] = smin[0]; qOut[i] = siq[0]; }
}

// ---------------- Kernel 3: third-class scan on row q[i], per-row loss -----
__global__ __launch_bounds__(256)
void pass2(const float* __restrict__ D, const int* __restrict__ tgt,
           const float* __restrict__ ap, const float* __restrict__ an,
           const int* __restrict__ pArr, const int* __restrict__ qArr,
           float* __restrict__ lossArr) {
    const int i = blockIdx.x, tid = threadIdx.x;
    const int q = qArr[i];
    const int ti = tgt[i], lq = tgt[q];
    const float* rowq = D + (size_t)q * N_DIM;
    float bmin = INFINITY; int br = -1;
#pragma unroll
    for (int it = 0; it < 4; ++it) {
        const int j0 = (it * 256 + tid) * 4;
        floatx4 d = *(const floatx4*)(rowq + j0);
        intx4 t4 = *(const intx4*)(tgt + j0);
#pragma unroll
        for (int e = 0; e < 4; ++e) {
            const int j = j0 + e; const float dv = d[e];
            if (t4[e] != ti && t4[e] != lq) {
                if (dv < bmin || (dv == bmin && j > br)) { bmin = dv; br = j; }
            }
        }
    }
    __shared__ float sm[256]; __shared__ int si[256];
    sm[tid] = bmin; si[tid] = br;
    __syncthreads();
    for (int off = 128; off; off >>= 1) {
        if (tid < off) {
            float v = sm[tid + off]; int ix = si[tid + off];
            if (v < sm[tid] || (v == sm[tid] && ix > si[tid])) { sm[tid] = v; si[tid] = ix; }
        }
        __syncthreads();
    }
    if (tid == 0) {
        const int r = si[0]; const float okmin = sm[0];
        const float an2 = D[(size_t)pArr[i] * N_DIM + q];
        const float an3 = D[(size_t)i * N_DIM + r];
        lossArr[i] = fmaxf(ap[i] - an[i], 0.f) + fabsf(an[i] - an2) + fabsf(an3 - okmin);
    }
}

// ---------------- Kernel 4: final sum / n -----------------------------------
__global__ __launch_bounds__(256)
void finred(const float* __restrict__ lossArr, float* __restrict__ out) {
    const int tid = threadIdx.x;
    float s = 0.f;
    for (int j = tid; j < N_DIM; j += 256) s += lossArr[j];
#pragma unroll
    for (int off = 32; off; off >>= 1) s += __shfl_down(s, off);
    __shared__ float w[4];
    const int wave = tid >> 6, lane = tid & 63;
    if (lane == 0) w[wave] = s;
    __syncthreads();
    if (tid == 0) out[0] = (w[0] + w[1] + w[2] + w[3]) * (1.0f / (float)N_DIM);
}

extern "C" void kernel_launch(void* const* d_in, const int* in_sizes, int n_in,
                              void* d_out, int out_size, void* d_ws, size_t ws_size,
                              hipStream_t stream) {
    const float* X = (const float*)d_in[0];
    const int* tgt = (const int*)d_in[1];
    float* out = (float*)d_out;

    char* w = (char*)d_ws;
    unsigned short* Abf = (unsigned short*)w;                 // 16 MB
    float* D = (float*)(w + ((size_t)16 << 20));              // 64 MB
    float* sq = (float*)(w + ((size_t)80 << 20));             // 16 KB
    float* ap = sq + N_DIM;
    float* an = ap + N_DIM;
    float* lossArr = an + N_DIM;
    int* pA = (int*)(lossArr + N_DIM);
    int* qA = pA + N_DIM;

    prep_kernel<<<N_DIM, 256, 0, stream>>>(X, Abf, sq);
    gemm_dist<<<256, 512, 0, stream>>>(Abf, sq, D);
    rowstats<<<N_DIM, 256, 0, stream>>>(D, tgt, ap, an, pA, qA);
    pass2<<<N_DIM, 256, 0, stream>>>(D, tgt, ap, an, pA, qA, lossArr);
    finred<<<1, 256, 0, stream>>>(lossArr, out);
}

// Round 4
// 108.157 us; speedup vs baseline: 1.2711x; 1.0149x over previous
//
#include <hip/hip_runtime.h>
#include <hip/hip_bf16.h>
#include <cstdint>

#define N_DIM 4096
#define K_DIM 2048
#define NIT 16   // 32 K-tiles of 64, 2 per iteration

typedef __bf16 bf16x8 __attribute__((ext_vector_type(8)));
typedef float floatx4 __attribute__((ext_vector_type(4)));
typedef unsigned short ushort8 __attribute__((ext_vector_type(8)));
typedef int intx4 __attribute__((ext_vector_type(4)));

__device__ __forceinline__ unsigned short f2bf(float f) {
    unsigned int u = __builtin_bit_cast(unsigned int, f);
    unsigned int r = (u + 0x7fffu + ((u >> 16) & 1u)) >> 16;  // RNE
    return (unsigned short)r;
}

__device__ __forceinline__ void gld_lds16(const void* g, void* l) {
    __builtin_amdgcn_global_load_lds(
        (const __attribute__((address_space(1))) unsigned int*)g,
        (__attribute__((address_space(3))) unsigned int*)l,
        16, 0, 0);
}

__device__ __forceinline__ void stage_half(const unsigned short* src, unsigned short* ldsWave) {
    gld_lds16(src, ldsWave);                       // rows 0-63 of the half
    gld_lds16(src + 64 * K_DIM, ldsWave + 4096);   // rows 64-127 (+8192 B)
}

// ---------------- Kernel 0: cast fp32 -> bf16, compute row squared norms ----
__global__ __launch_bounds__(256)
void prep_kernel(const float* __restrict__ X, unsigned short* __restrict__ Abf,
                 float* __restrict__ sq) {
    const int row = blockIdx.x;
    const int tid = threadIdx.x;
    const float* xr = X + (size_t)row * K_DIM;
    floatx4 a = *(const floatx4*)(xr + tid * 8);
    floatx4 b = *(const floatx4*)(xr + tid * 8 + 4);
    float s = 0.f;
    ushort8 o;
#pragma unroll
    for (int e = 0; e < 4; ++e) {
        s += a[e] * a[e] + b[e] * b[e];
        o[e] = f2bf(a[e]);
        o[4 + e] = f2bf(b[e]);
    }
    *(ushort8*)(Abf + (size_t)row * K_DIM + tid * 8) = o;
#pragma unroll
    for (int off = 32; off; off >>= 1) s += __shfl_down(s, off);
    __shared__ float wsum[4];
    const int wave = tid >> 6, lane = tid & 63;
    if (lane == 0) wsum[wave] = s;
    __syncthreads();
    if (tid == 0) sq[row] = wsum[0] + wsum[1] + wsum[2] + wsum[3];
}

// ---------------- Kernel 1: 256x256 8-phase bf16 MFMA GEMM + dist epilogue --
// 512 thr = 8 waves (2Mx4N). BK=64, 2 K-tiles/iter. Single barrier per phase;
// quadrant order (0,0),(0,1),(1,1),(1,0); A-half held across 2 phases.
// Reads/K-tile/wave: 12,4,8,4 = 28 b128. XOR-swizzle (row&7)<<4 via
// pre-swizzled global source + swizzled ds_read (rule #21).
// LDS byte regions: buf0: A0=0 A1=16384 B0=32768 B1=49152; buf1: +65536.
#define RD_A(OFF) { _Pragma("unroll") for (int m_ = 0; m_ < 4; ++m_) { \
    _Pragma("unroll") for (int kk_ = 0; kk_ < 2; ++kk_) { \
        af[m_][kk_] = *(const bf16x8*)(ldsc + (OFF) + rA[m_] + kb[kk_]); } } }
#define RD_B(OFF) { _Pragma("unroll") for (int n_ = 0; n_ < 2; ++n_) { \
    _Pragma("unroll") for (int kk_ = 0; kk_ < 2; ++kk_) { \
        bfv[n_][kk_] = *(const bf16x8*)(ldsc + (OFF) + rB[n_] + kb[kk_]); } } }
#define MMQ(MH, NH) { _Pragma("unroll") for (int m_ = 0; m_ < 4; ++m_) { \
    _Pragma("unroll") for (int n_ = 0; n_ < 2; ++n_) { \
    _Pragma("unroll") for (int kk_ = 0; kk_ < 2; ++kk_) { \
        acc[MH][NH][m_][n_] = __builtin_amdgcn_mfma_f32_16x16x32_bf16( \
            af[m_][kk_], bfv[n_][kk_], acc[MH][NH][m_][n_], 0, 0, 0); } } } }
#define BAR() __builtin_amdgcn_s_barrier()
#define PRIO1() __builtin_amdgcn_s_setprio(1)
#define PRIO0() __builtin_amdgcn_s_setprio(0)
#define VMCNT2() asm volatile("s_waitcnt vmcnt(2)" ::: "memory")
#define VMCNT0() asm volatile("s_waitcnt vmcnt(0)" ::: "memory")

__global__ __launch_bounds__(512, 2)
void gemm_dist(const unsigned short* __restrict__ Abf, const float* __restrict__ sq,
               float* __restrict__ D) {
    __shared__ unsigned short lds[65536];   // 128 KB
    const char* ldsc = (const char*)lds;
    const int tid = threadIdx.x;
    const int wid = tid >> 6, lane = tid & 63;
    const int wr = wid >> 2, wc = wid & 3;
    const int fr = lane & 15;
    const int key = (fr & 7) << 4;
    const int klin = (lane >> 4) << 4;     // byte offset of 16B k-slot
    int kb[2];
    kb[0] = klin ^ key;
    kb[1] = (64 | klin) ^ key;
    int rA[4], rB[2];
#pragma unroll
    for (int m = 0; m < 4; ++m) rA[m] = (wr * 64 + m * 16 + fr) * 128;
#pragma unroll
    for (int n = 0; n < 2; ++n) rB[n] = (wc * 32 + n * 16 + fr) * 128;

    const int swz = (blockIdx.x & 7) * 32 + (blockIdx.x >> 3);  // XCD-chunked
    const int bi = swz >> 4, bj = swz & 15;
    const int rowC0 = bi * 256, colC0 = bj * 256;

    // per-thread staging source (inverse-swizzled k: linear LDS + swz read = identity)
    const int srow = tid >> 3;
    const int ksrc = ((tid & 7) ^ (srow & 7)) << 3;
    const unsigned short* aSt = Abf + (size_t)(rowC0 + srow) * K_DIM + ksrc;
    const unsigned short* bSt = Abf + (size_t)(colC0 + srow) * K_DIM + ksrc;
    // wave-uniform LDS stage bases (ushort offsets = byte/2 + wid*512)
    unsigned short* Lb0A0 = lds + 0     + wid * 512;
    unsigned short* Lb0A1 = lds + 8192  + wid * 512;
    unsigned short* Lb0B0 = lds + 16384 + wid * 512;
    unsigned short* Lb0B1 = lds + 24576 + wid * 512;
    unsigned short* Lb1A0 = lds + 32768 + wid * 512;
    unsigned short* Lb1A1 = lds + 40960 + wid * 512;
    unsigned short* Lb1B0 = lds + 49152 + wid * 512;
    unsigned short* Lb1B1 = lds + 57344 + wid * 512;

    floatx4 acc[2][2][4][2];
#pragma unroll
    for (int a0 = 0; a0 < 2; ++a0)
#pragma unroll
    for (int a1 = 0; a1 < 2; ++a1)
#pragma unroll
    for (int a2 = 0; a2 < 4; ++a2)
#pragma unroll
    for (int a3 = 0; a3 < 2; ++a3) acc[a0][a1][a2][a3] = (floatx4){0.f, 0.f, 0.f, 0.f};
    bf16x8 af[4][2], bfv[2][2];

    // prologue: tile0 {A0,B0,A1,B1} + tile1.A0  (10 loads; vmcnt(2) = tile0 landed)
    stage_half(aSt,          Lb0A0);
    stage_half(bSt,          Lb0B0);
    stage_half(aSt + 262144, Lb0A1);
    stage_half(bSt + 262144, Lb0B1);
    stage_half(aSt + 64,     Lb1A0);
    VMCNT2();
    BAR();

    for (int it = 0; it < NIT; ++it) {
        const int t64 = it * 128;           // k-elem base of tile a=2*it
        const bool pf = (it < NIT - 1);
        // ph1: Q(0,0) <- A0,B0            | stage (a+1).B0 -> buf1.B0
        RD_A(0); RD_B(32768);
        stage_half(bSt + t64 + 64, Lb1B0);
        PRIO1(); MMQ(0, 0); PRIO0(); BAR();
        // ph2: Q(0,1) <- A0(held),B1      | stage (a+1).A1 -> buf1.A1
        RD_B(49152);
        stage_half(aSt + 262144 + t64 + 64, Lb1A1);
        PRIO1(); MMQ(0, 1); PRIO0(); BAR();
        // ph3: Q(1,1) <- A1,B1(held)      | stage (a+1).B1 -> buf1.B1
        RD_A(16384);
        stage_half(bSt + 262144 + t64 + 64, Lb1B1);
        PRIO1(); MMQ(1, 1); PRIO0(); BAR();
        // ph4: Q(1,0) <- A1(held),B0      | stage (a+2).A0 -> buf0.A0
        RD_B(32768);
        if (pf) stage_half(aSt + t64 + 128, Lb0A0);
        PRIO1(); MMQ(1, 0); PRIO0();
        if (pf) { VMCNT2(); } else { VMCNT0(); }   // tile a+1 fully landed
        BAR();
        // ph5: buf1 Q(0,0)                | stage (a+2).B1 -> buf0.B1
        RD_A(65536); RD_B(98304);
        if (pf) stage_half(bSt + 262144 + t64 + 128, Lb0B1);
        PRIO1(); MMQ(0, 0); PRIO0(); BAR();
        // ph6: Q(0,1)                     | stage (a+2).A1 -> buf0.A1
        RD_B(114688);
        if (pf) stage_half(aSt + 262144 + t64 + 128, Lb0A1);
        PRIO1(); MMQ(0, 1); PRIO0(); BAR();
        // ph7: Q(1,1)                     | stage (a+2).B0 -> buf0.B0
        RD_A(81920);
        if (pf) stage_half(bSt + t64 + 128, Lb0B0);
        PRIO1(); MMQ(1, 1); PRIO0(); BAR();
        // ph8: Q(1,0)                     | stage (a+3).A0 -> buf1.A0
        RD_B(98304);
        if (pf) stage_half(aSt + t64 + 192, Lb1A0);
        PRIO1(); MMQ(1, 0); PRIO0();
        if (pf) { VMCNT2(); } else { VMCNT0(); }   // tile a+2 fully landed
        BAR();
    }

    // epilogue: D[i][j] = sqrt(max(sq_i + sq_j - 2*dot, 1e-12))
#pragma unroll
    for (int MH = 0; MH < 2; ++MH)
#pragma unroll
    for (int NH = 0; NH < 2; ++NH)
#pragma unroll
    for (int m = 0; m < 4; ++m)
#pragma unroll
    for (int n = 0; n < 2; ++n) {
        const int col = colC0 + NH * 128 + wc * 32 + n * 16 + fr;
        const int row0 = rowC0 + MH * 128 + wr * 64 + m * 16 + (lane >> 4) * 4;
        const float sqc = sq[col];
#pragma unroll
        for (int r = 0; r < 4; ++r) {
            float d2 = sq[row0 + r] + sqc - 2.0f * acc[MH][NH][m][n][r];
            D[(size_t)(row0 + r) * N_DIM + col] = sqrtf(fmaxf(d2, 1e-12f));
        }
    }
}

// ---------------- Kernel 2: per-row hardest-pos / hardest-neg --------------
__global__ __launch_bounds__(256)
void rowstats(const float* __restrict__ D, const int* __restrict__ tgt,
              float* __restrict__ ap, float* __restrict__ an,
              int* __restrict__ pOut, int* __restrict__ qOut) {
    const int i = blockIdx.x, tid = threadIdx.x;
    const int ti = tgt[i];
    const float* row = D + (size_t)i * N_DIM;
    float bmax = -INFINITY; int bp = -1;
    float bmin = INFINITY;  int bq = -1;
#pragma unroll
    for (int it = 0; it < 4; ++it) {
        const int j0 = (it * 256 + tid) * 4;
        floatx4 d = *(const floatx4*)(row + j0);
        intx4 t4 = *(const intx4*)(tgt + j0);
#pragma unroll
        for (int e = 0; e < 4; ++e) {
            const int j = j0 + e; const float dv = d[e];
            if (t4[e] == ti) {
                if (dv > bmax || (dv == bmax && j > bp)) { bmax = dv; bp = j; }
            } else {
                if (dv < bmin || (dv == bmin && j > bq)) { bmin = dv; bq = j; }
            }
        }
    }
    __shared__ float smax[256]; __shared__ int sip[256];
    __shared__ float smin[256]; __shared__ int siq[256];
    smax[tid] = bmax; sip[tid] = bp; smin[tid] = bmin; siq[tid] = bq;
    __syncthreads();
    for (int off = 128; off; off >>= 1) {
        if (tid < off) {
            float v = smax[tid + off]; int ix = sip[tid + off];
            if (v > smax[tid] || (v == smax[tid] && ix > sip[tid])) { smax[tid] = v; sip[tid] = ix; }
            float w = smin[tid + off]; int iy = siq[tid + off];
            if (w < smin[tid] || (w == smin[tid] && iy > siq[tid])) { smin[tid] = w; siq[tid] = iy; }
        }
        __syncthreads();
    }
    if (tid == 0) { ap[i] = smax[0]; pOut[i] = sip[0]; an[i] = smin[0]; qOut[i] = siq[0]; }
}

// ---------------- Kernel 3: third-class scan on row q[i], per-row loss -----
__global__ __launch_bounds__(256)
void pass2(const float* __restrict__ D, const int* __restrict__ tgt,
           const float* __restrict__ ap, const float* __restrict__ an,
           const int* __restrict__ pArr, const int* __restrict__ qArr,
           float* __restrict__ lossArr) {
    const int i = blockIdx.x, tid = threadIdx.x;
    const int q = qArr[i];
    const int ti = tgt[i], lq = tgt[q];
    const float* rowq = D + (size_t)q * N_DIM;
    float bmin = INFINITY; int br = -1;
#pragma unroll
    for (int it = 0; it < 4; ++it) {
        const int j0 = (it * 256 + tid) * 4;
        floatx4 d = *(const floatx4*)(rowq + j0);
        intx4 t4 = *(const intx4*)(tgt + j0);
#pragma unroll
        for (int e = 0; e < 4; ++e) {
            const int j = j0 + e; const float dv = d[e];
            if (t4[e] != ti && t4[e] != lq) {
                if (dv < bmin || (dv == bmin && j > br)) { bmin = dv; br = j; }
            }
        }
    }
    __shared__ float sm[256]; __shared__ int si[256];
    sm[tid] = bmin; si[tid] = br;
    __syncthreads();
    for (int off = 128; off; off >>= 1) {
        if (tid < off) {
            float v = sm[tid + off]; int ix = si[tid + off];
            if (v < sm[tid] || (v == sm[tid] && ix > si[tid])) { sm[tid] = v; si[tid] = ix; }
        }
        __syncthreads();
    }
    if (tid == 0) {
        const int r = si[0]; const float okmin = sm[0];
        const float an2 = D[(size_t)pArr[i] * N_DIM + q];
        const float an3 = D[(size_t)i * N_DIM + r];
        lossArr[i] = fmaxf(ap[i] - an[i], 0.f) + fabsf(an[i] - an2) + fabsf(an3 - okmin);
    }
}

// ---------------- Kernel 4: final sum / n -----------------------------------
__global__ __launch_bounds__(256)
void finred(const float* __restrict__ lossArr, float* __restrict__ out) {
    const int tid = threadIdx.x;
    float s = 0.f;
    for (int j = tid; j < N_DIM; j += 256) s += lossArr[j];
#pragma unroll
    for (int off = 32; off; off >>= 1) s += __shfl_down(s, off);
    __shared__ float w[4];
    const int wave = tid >> 6, lane = tid & 63;
    if (lane == 0) w[wave] = s;
    __syncthreads();
    if (tid == 0) out[0] = (w[0] + w[1] + w[2] + w[3]) * (1.0f / (float)N_DIM);
}

extern "C" void kernel_launch(void* const* d_in, const int* in_sizes, int n_in,
                              void* d_out, int out_size, void* d_ws, size_t ws_size,
                              hipStream_t stream) {
    const float* X = (const float*)d_in[0];
    const int* tgt = (const int*)d_in[1];
    float* out = (float*)d_out;

    char* w = (char*)d_ws;
    unsigned short* Abf = (unsigned short*)w;                 // 16 MB
    float* D = (float*)(w + ((size_t)16 << 20));              // 64 MB
    float* sq = (float*)(w + ((size_t)80 << 20));             // 16 KB
    float* ap = sq + N_DIM;
    float* an = ap + N_DIM;
    float* lossArr = an + N_DIM;
    int* pA = (int*)(lossArr + N_DIM);
    int* qA = pA + N_DIM;

    prep_kernel<<<N_DIM, 256, 0, stream>>>(X, Abf, sq);
    gemm_dist<<<256, 512, 0, stream>>>(Abf, sq, D);
    rowstats<<<N_DIM, 256, 0, stream>>>(D, tgt, ap, an, pA, qA);
    pass2<<<N_DIM, 256, 0, stream>>>(D, tgt, ap, an, pA, qA, lossArr);
    finred<<<1, 256, 0, stream>>>(lossArr, out);
}